// Round 16
// baseline (158.454 us; speedup 1.0000x reference)
//
#include <hip/hip_runtime.h>

// SAGAN self-attention, B=4 C=256 H=W=64 (N=4096), CK=32.
//   f = fw@x+fb, g = gw@x+gb, hv = hw@x+hb         (channel 1x1 convs)
//   s[j,m] = sum_k f[k,j] g[k,m];  L[j] = sum_m exp(s[j,m])
//   w[c,j] = hv[c,j]/L[j];  sa[c,m] = sum_j w[c,j] exp(s[j,m]);  out = gamma*sa+x
//
// exp2 pipeline: fgT stores f*log2(e) -> exp2(f'.g) == exp(s), bare v_exp_f32.
// R14 lesson: conflicts=0 didn't move the wall — the binder is the serial
// MFMA1 -> exp2 -> MFMA2 chain per iteration. This round pipelines E one tile
// ahead: MFMA1/exp2(it+1) overlap MFMA2(it) (independent -> matrix pipe stays
// fed, exp2 co-issues on TRANS while MFMA2 executes).
//
// ws layout (bytes) — total 10,747,904:
//   fgT  [4][4096][64]  bf16  @ 0         [n][o]: o<32 = f^T*log2e, o>=32 = g^T
//   hv/w [4][256][4096] bf16  @ 2097152   proj writes hv; wdiv -> w (kappa-packed)
//   Lp   [4][4][4096]   f32   @ 10485760  partial L sums (4 m-splits)
//
// XCD map (grid%8==0): b=(bid&7)>>1 pins each batch's fgT+w to one XCD pair L2.

typedef __bf16 bf16x4 __attribute__((ext_vector_type(4)));
typedef __bf16 bf16x8 __attribute__((ext_vector_type(8)));
typedef float  f32x4  __attribute__((ext_vector_type(4)));

static __device__ __forceinline__ bf16x8 cvt8(f32x4 lo, f32x4 hi) {
  bf16x8 r;
  r[0]=(__bf16)lo[0]; r[1]=(__bf16)lo[1]; r[2]=(__bf16)lo[2]; r[3]=(__bf16)lo[3];
  r[4]=(__bf16)hi[0]; r[5]=(__bf16)hi[1]; r[6]=(__bf16)hi[2]; r[7]=(__bf16)hi[3];
  return r;
}
// kappa k-map (tied to MFMA D output): e -> k = h*4 + (e&3) + 16*(e>>2).
// Free axes (channel contraction): e -> k = h*8 + e (single 16B load).

// ---------------- proj: x read ONCE; block = 64 n-cols x all 320 m-rows ----------
__global__ __launch_bounds__(512, 1) void k_proj(
    const float* __restrict__ fw, const float* __restrict__ gw,
    const float* __restrict__ hw, const float* __restrict__ x,
    const float* __restrict__ fb, const float* __restrict__ gb,
    const float* __restrict__ hb,
    __bf16* __restrict__ fgT, __bf16* __restrict__ hv) {
  __shared__ __bf16 Bs[2][64][40];
  const int bid = blockIdx.x;
  const int b = (bid & 7) >> 1;
  const int n0 = (((bid >> 3) << 1) | (bid & 1)) * 64;
  const int t = threadIdx.x, w = t >> 6, lane = t & 63, r16 = lane & 15, h = lane >> 4;
  const int nsub = w & 1, mq = w >> 1;
  const float* xb = x + (size_t)b * (256 * 4096);
  const float* Wp[5];
  #pragma unroll
  for (int mt = 0; mt < 5; ++mt) {
    const int wrow = mq * 80 + mt * 16 + r16;
    Wp[mt] = wrow < 32 ? (fw + wrow * 256)
           : wrow < 64 ? (gw + (wrow - 32) * 256)
                       : (hw + (wrow - 64) * 256);
  }
  const int kk = t >> 4, nc = (t & 15) * 4;
  f32x4 acc[5][2] = {};
  {
    f32x4 xv = *(const f32x4*)&xb[(size_t)kk * 4096 + n0 + nc];
    Bs[0][nc + 0][kk] = (__bf16)xv[0]; Bs[0][nc + 1][kk] = (__bf16)xv[1];
    Bs[0][nc + 2][kk] = (__bf16)xv[2]; Bs[0][nc + 3][kk] = (__bf16)xv[3];
  }
  __syncthreads();
  for (int ks = 0; ks < 8; ++ks) {
    const int cur = ks & 1;
    f32x4 xn;
    if (ks < 7) xn = *(const f32x4*)&xb[(size_t)((ks + 1) * 32 + kk) * 4096 + n0 + nc];
    bf16x8 bf0 = *(const bf16x8*)&Bs[cur][nsub * 32 + r16][h * 8];
    bf16x8 bf1 = *(const bf16x8*)&Bs[cur][nsub * 32 + 16 + r16][h * 8];
    #pragma unroll
    for (int mt = 0; mt < 5; ++mt) {
      f32x4 wlo = *(const f32x4*)(Wp[mt] + ks * 32 + h * 8);
      f32x4 whi = *(const f32x4*)(Wp[mt] + ks * 32 + h * 8 + 4);
      bf16x8 af = cvt8(wlo, whi);
      acc[mt][0] = __builtin_amdgcn_mfma_f32_16x16x32_bf16(af, bf0, acc[mt][0], 0, 0, 0);
      acc[mt][1] = __builtin_amdgcn_mfma_f32_16x16x32_bf16(af, bf1, acc[mt][1], 0, 0, 0);
    }
    if (ks < 7) {
      const int nxt = cur ^ 1;
      Bs[nxt][nc + 0][kk] = (__bf16)xn[0]; Bs[nxt][nc + 1][kk] = (__bf16)xn[1];
      Bs[nxt][nc + 2][kk] = (__bf16)xn[2]; Bs[nxt][nc + 3][kk] = (__bf16)xn[3];
    }
    __syncthreads();
  }
  #pragma unroll
  for (int mt = 0; mt < 5; ++mt) {
    #pragma unroll
    for (int nt = 0; nt < 2; ++nt) {
      const int nn = n0 + nsub * 32 + nt * 16 + r16;
      #pragma unroll
      for (int r = 0; r < 4; ++r) {
        const int row = mq * 80 + mt * 16 + h * 4 + r;  // C/D: row=(lane>>4)*4+reg
        const float bias = row < 32 ? fb[row] : (row < 64 ? gb[row - 32] : hb[row - 64]);
        float val = acc[mt][nt][r] + bias;
        if (row < 32) val *= 1.44269504089f;            // f * log2(e)
        if (row < 64) fgT[((size_t)b * 4096 + nn) * 64 + row] = (__bf16)val;
        else          hv[((size_t)b * 256 + (row - 64)) * 4096 + nn] = (__bf16)val;
      }
    }
  }
}

// ---------------- pass1: L[i] = sum_m exp2(f'_i . g_m)  (partial, m-quarter) ----
__global__ __launch_bounds__(256) void k_pass1(const __bf16* __restrict__ fgT,
                                               float* __restrict__ Lp) {
  const int bid = blockIdx.x;
  const int b = (bid & 7) >> 1;
  const int sub = ((bid >> 3) << 1) | (bid & 1);
  const int ms = sub >> 6, ib = sub & 63;
  const int w = threadIdx.x >> 6, lane = threadIdx.x & 63, r16 = lane & 15, h = lane >> 4;
  const int ibase = ib * 64 + w * 16;
  const __bf16* fg = fgT + (size_t)b * (4096 * 64);
  const bf16x8 afrag = *(const bf16x8*)(fg + (size_t)(ibase + r16) * 64 + h * 8);
  const f32x4 zero = {};
  float ls0 = 0.f, ls1 = 0.f, ls2 = 0.f, ls3 = 0.f;
  for (int mt = 0; mt < 64; mt += 2) {
    const int mb = ms * 1024 + mt * 16;
    bf16x8 g0 = *(const bf16x8*)(fg + (size_t)(mb + r16) * 64 + 32 + h * 8);
    bf16x8 g1 = *(const bf16x8*)(fg + (size_t)(mb + 16 + r16) * 64 + 32 + h * 8);
    f32x4 d0 = __builtin_amdgcn_mfma_f32_16x16x32_bf16(afrag, g0, zero, 0, 0, 0);
    f32x4 d1 = __builtin_amdgcn_mfma_f32_16x16x32_bf16(afrag, g1, zero, 0, 0, 0);
    ls0 += __builtin_amdgcn_exp2f(d0[0]) + __builtin_amdgcn_exp2f(d1[0]);
    ls1 += __builtin_amdgcn_exp2f(d0[1]) + __builtin_amdgcn_exp2f(d1[1]);
    ls2 += __builtin_amdgcn_exp2f(d0[2]) + __builtin_amdgcn_exp2f(d1[2]);
    ls3 += __builtin_amdgcn_exp2f(d0[3]) + __builtin_amdgcn_exp2f(d1[3]);
  }
  #pragma unroll
  for (int off = 1; off < 16; off <<= 1) {
    ls0 += __shfl_xor(ls0, off); ls1 += __shfl_xor(ls1, off);
    ls2 += __shfl_xor(ls2, off); ls3 += __shfl_xor(ls3, off);
  }
  if (r16 == 0) {
    f32x4 o = {ls0, ls1, ls2, ls3};
    *(f32x4*)&Lp[(size_t)(b * 4 + ms) * 4096 + ibase + h * 4] = o;
  }
}

// ---------------- wdiv: w = hv/L, kappa-packed cols, in place ----------------
__global__ __launch_bounds__(256) void k_wdiv(__bf16* __restrict__ hv,
                                              const float* __restrict__ Lp) {
  const int bid = blockIdx.x;                       // 512
  const int b = (bid & 7) >> 1;
  const int chunk = ((bid >> 3) << 1) | (bid & 1);  // 0..127 -> 2 rows each
  const int t = threadIdx.x;
  const int row = chunk * 2 + (t >> 7);
  const int col = (t & 127) * 32;
  __bf16* p = hv + ((size_t)b * 256 + row) * 4096 + col;
  const float* lp = Lp + (size_t)b * 16384 + col;
  float L[32];
  #pragma unroll
  for (int i = 0; i < 32; i += 4) {
    f32x4 Lv = *(const f32x4*)(lp + i);
    Lv += *(const f32x4*)(lp + i + 4096);
    Lv += *(const f32x4*)(lp + i + 8192);
    Lv += *(const f32x4*)(lp + i + 12288);
    L[i] = Lv[0]; L[i+1] = Lv[1]; L[i+2] = Lv[2]; L[i+3] = Lv[3];
  }
  bf16x4 in[8];
  #pragma unroll
  for (int k = 0; k < 8; ++k) in[k] = *(const bf16x4*)(p + k * 4);
  bf16x4 ov[8];
  #pragma unroll
  for (int h = 0; h < 4; ++h)
    #pragma unroll
    for (int s = 0; s < 2; ++s) {
      bf16x4 v = in[s * 4 + h];                     // old chunk at 16s+4h
      bf16x4 o;
      #pragma unroll
      for (int bb = 0; bb < 4; ++bb)
        o[bb] = (__bf16)((float)v[bb] / L[16 * s + 4 * h + bb]);
      ov[2 * h + s] = o;                            // new chunk at 8h+4s
    }
  #pragma unroll
  for (int k = 0; k < 8; ++k) *(bf16x4*)(p + k * 4) = ov[k];
}

// ---------------- pass2: E-pipelined. sa[c,m]=sum_j w[c,j]E[j,m]; out=gm*sa+x ----
// R14 geometry (conflicts=0) + E one tile ahead: iter `it` computes
// MFMA1/exp2 for tile it+1 while MFMA2 consumes ef_cur (tile it). The two
// MFMA groups are independent -> matrix pipe stays fed; exp2 co-issues on the
// TRANS pipe during MFMA2 execution. Order: prefetch, LDS a-reads, MFMA1x4,
// MFMA2x8, exp2x16, stage-write, barrier.
__global__ __launch_bounds__(256, 4) void k_pass2(const __bf16* __restrict__ fgT,
    const __bf16* __restrict__ wbf, const float* __restrict__ x,
    const float* __restrict__ gamma, float* __restrict__ out) {
  __shared__ __bf16 wS[2][64][64];   // 16,384 B, swizzled
  const int bid = blockIdx.x;
  const int b = (bid & 7) >> 1;                     // XCD pair per batch
  const int cq = (bid >> 3) & 3;                    // c-quarter: rows cq*64..+63
  const int mblk = ((bid >> 5) << 1) | (bid & 1);   // 0..63
  const int t = threadIdx.x, w = t >> 6, lane = t & 63, r16 = lane & 15, h = lane >> 4;
  const int jh = w & 1, msub = w >> 1;
  const int mbase = mblk * 64 + msub * 32;
  const __bf16* fg = fgT + (size_t)b * (4096 * 64);
  const __bf16* wb = wbf + ((size_t)b * 256 + cq * 64) * 4096;
  // gfrags: MFMA1 B operands (contiguous channel map), invariant over j
  const bf16x8 gf0 = *(const bf16x8*)(fg + (size_t)(mbase + r16) * 64 + 32 + h * 8);
  const bf16x8 gf1 = *(const bf16x8*)(fg + (size_t)(mbase + 16 + r16) * 64 + 32 + h * 8);
  // staging: thread t covers row t>>2 (of 64), 16 j-elems (32B) at (t&3)*16
  const int srow = t >> 2, q = t & 3;
  const int sw = (srow & 7) << 4;                   // write-side XOR
  const __bf16* sgsrc = wb + (size_t)srow * 4096 + q * 16;
  char* sb0 = (char*)&wS[0][srow][0];
  char* sb1 = (char*)&wS[1][srow][0];
  const int c32 = q * 32;
  const int rsw = (r16 & 7) << 4;                   // read-side XOR
  const int roff = ((jh * 64 + h * 16) ^ rsw);      // kappa-packed b128 read
  const int jwave = jh * 32, h8 = h * 8;
  const f32x4 zero = {};

  f32x4 acc[4] = {};
  f32x4 acc2[4] = {};                               // second m-tile

  // prologue: stage w(0); compute E(0) in registers; load f(1)
  *(uint4*)(sb0 + ((c32 +  0) ^ sw)) = *(const uint4*)(sgsrc);
  *(uint4*)(sb0 + ((c32 + 16) ^ sw)) = *(const uint4*)(sgsrc + 8);
  bf16x8 fq0 = *(const bf16x8*)(fg + (size_t)(jwave + r16) * 64 + h8);
  bf16x8 fq1 = *(const bf16x8*)(fg + (size_t)(jwave + 16 + r16) * 64 + h8);
  bf16x8 ef0, ef1;                                  // E(it) for MFMA2
  {
    f32x4 d0 = __builtin_amdgcn_mfma_f32_16x16x32_bf16(fq0, gf0, zero, 0, 0, 0);
    f32x4 d1 = __builtin_amdgcn_mfma_f32_16x16x32_bf16(fq1, gf0, zero, 0, 0, 0);
    f32x4 d2 = __builtin_amdgcn_mfma_f32_16x16x32_bf16(fq0, gf1, zero, 0, 0, 0);
    f32x4 d3 = __builtin_amdgcn_mfma_f32_16x16x32_bf16(fq1, gf1, zero, 0, 0, 0);
    #pragma unroll
    for (int r = 0; r < 4; ++r) {
      ef0[r]     = (__bf16)__builtin_amdgcn_exp2f(d0[r]);
      ef0[4 + r] = (__bf16)__builtin_amdgcn_exp2f(d1[r]);
      ef1[r]     = (__bf16)__builtin_amdgcn_exp2f(d2[r]);
      ef1[4 + r] = (__bf16)__builtin_amdgcn_exp2f(d3[r]);
    }
  }
  fq0 = *(const bf16x8*)(fg + (size_t)(64 + jwave + r16) * 64 + h8);   // f(1)
  fq1 = *(const bf16x8*)(fg + (size_t)(64 + jwave + 16 + r16) * 64 + h8);
  __syncthreads();

  for (int it = 0; it < 64; ++it) {
    const int cur = it & 1;
    const int jbn = (it + 1) * 64;                  // w tile it+1
    const int jbn2 = (it + 2) * 64;                 // f tile it+2 (benign overrun)
    uint4 pw0, pw1; bf16x8 nf0, nf1;
    if (it < 63) {   // prefetch next-tile staging + next-next f frags
      pw0 = *(const uint4*)(sgsrc + jbn);
      pw1 = *(const uint4*)(sgsrc + jbn + 8);
      nf0 = *(const bf16x8*)(fg + (size_t)(jbn2 + jwave + r16) * 64 + h8);
      nf1 = *(const bf16x8*)(fg + (size_t)(jbn2 + jwave + 16 + r16) * 64 + h8);
    }
    // LDS a-frags for tile it (one b128 each, kappa-packed)
    bf16x8 a0 = *(const bf16x8*)((const char*)&wS[cur][ 0 + r16][0] + roff);
    bf16x8 a1 = *(const bf16x8*)((const char*)&wS[cur][16 + r16][0] + roff);
    bf16x8 a2 = *(const bf16x8*)((const char*)&wS[cur][32 + r16][0] + roff);
    bf16x8 a3 = *(const bf16x8*)((const char*)&wS[cur][48 + r16][0] + roff);
    // MFMA1 x4 for tile it+1 (independent of MFMA2 below)
    f32x4 d0, d1, d2, d3;
    if (it < 63) {
      d0 = __builtin_amdgcn_mfma_f32_16x16x32_bf16(fq0, gf0, zero, 0, 0, 0);
      d1 = __builtin_amdgcn_mfma_f32_16x16x32_bf16(fq1, gf0, zero, 0, 0, 0);
      d2 = __builtin_amdgcn_mfma_f32_16x16x32_bf16(fq0, gf1, zero, 0, 0, 0);
      d3 = __builtin_amdgcn_mfma_f32_16x16x32_bf16(fq1, gf1, zero, 0, 0, 0);
    }
    // MFMA2 x8 for tile it (uses ef from previous iteration)
    acc[0]  = __builtin_amdgcn_mfma_f32_16x16x32_bf16(a0, ef0, acc[0],  0, 0, 0);
    acc2[0] = __builtin_amdgcn_mfma_f32_16x16x32_bf16(a0, ef1, acc2[0], 0, 0, 0);
    acc[1]  = __builtin_amdgcn_mfma_f32_16x16x32_bf16(a1, ef0, acc[1],  0, 0, 0);
    acc2[1] = __builtin_amdgcn_mfma_f32_16x16x32_bf16(a1, ef1, acc2[1], 0, 0, 0);
    acc[2]  = __builtin_amdgcn_mfma_f32_16x16x32_bf16(a2, ef0, acc[2],  0, 0, 0);
    acc2[2] = __builtin_amdgcn_mfma_f32_16x16x32_bf16(a2, ef1, acc2[2], 0, 0, 0);
    acc[3]  = __builtin_amdgcn_mfma_f32_16x16x32_bf16(a3, ef0, acc[3],  0, 0, 0);
    acc2[3] = __builtin_amdgcn_mfma_f32_16x16x32_bf16(a3, ef1, acc2[3], 0, 0, 0);
    if (it < 63) {
      // exp2 -> E(it+1) (TRANS pipe, overlaps MFMA2 execution)
      #pragma unroll
      for (int r = 0; r < 4; ++r) {
        ef0[r]     = (__bf16)__builtin_amdgcn_exp2f(d0[r]);
        ef0[4 + r] = (__bf16)__builtin_amdgcn_exp2f(d1[r]);
        ef1[r]     = (__bf16)__builtin_amdgcn_exp2f(d2[r]);
        ef1[4 + r] = (__bf16)__builtin_amdgcn_exp2f(d3[r]);
      }
      // stage w(it+1) into the other buffer; advance f frags
      char* sd = cur ? sb0 : sb1;
      *(uint4*)(sd + ((c32 +  0) ^ sw)) = pw0;
      *(uint4*)(sd + ((c32 + 16) ^ sw)) = pw1;
      fq0 = nf0; fq1 = nf1;
    }
    __syncthreads();
  }

  // jh reduction: jh=1 waves dump partials into wS (dead), jh=0 adds + epilogue.
  float* red = (float*)wS;
  const int region = msub * 2048;                   // 2 regions x 8KB (floats)
  if (jh == 1) {
    #pragma unroll
    for (int ct = 0; ct < 4; ++ct) {
      *(f32x4*)&red[region + ((ct * 2 + 0) * 64 + lane) * 4] = acc[ct];
      *(f32x4*)&red[region + ((ct * 2 + 1) * 64 + lane) * 4] = acc2[ct];
    }
  }
  __syncthreads();
  if (jh == 0) {
    const float gm = gamma[0];
    const float* xb = x + (size_t)b * (256 * 4096);
    float* ob = out + (size_t)b * (256 * 4096);
    #pragma unroll
    for (int ct = 0; ct < 4; ++ct) {
      #pragma unroll
      for (int mt = 0; mt < 2; ++mt) {
        f32x4 o = *(const f32x4*)&red[region + ((ct * 2 + mt) * 64 + lane) * 4];
        o += (mt == 0) ? acc[ct] : acc2[ct];
        #pragma unroll
        for (int r = 0; r < 4; ++r) {
          const int c = cq * 64 + ct * 16 + h * 4 + r;
          const size_t idx = (size_t)c * 4096 + (mbase + mt * 16 + r16);
          ob[idx] = gm * o[r] + xb[idx];
        }
      }
    }
  }
}

extern "C" void kernel_launch(void* const* d_in, const int* in_sizes, int n_in,
                              void* d_out, int out_size, void* d_ws, size_t ws_size,
                              hipStream_t stream) {
  const float* x     = (const float*)d_in[0];
  const float* fw    = (const float*)d_in[1];
  const float* fb    = (const float*)d_in[2];
  const float* gw    = (const float*)d_in[3];
  const float* gb    = (const float*)d_in[4];
  const float* hw    = (const float*)d_in[5];
  const float* hb    = (const float*)d_in[6];
  const float* gamma = (const float*)d_in[7];
  float* out = (float*)d_out;

  char* wsb = (char*)d_ws;
  __bf16* fgT = (__bf16*)(wsb);
  __bf16* hv  = (__bf16*)(wsb + 2097152);
  float*  Lp  = (float*) (wsb + 10485760);

  k_proj<<<dim3(256), dim3(512), 0, stream>>>(fw, gw, hw, x, fb, gb, hb, fgT, hv);
  k_pass1<<<dim3(1024), dim3(256), 0, stream>>>(fgT, Lp);
  k_wdiv<<<dim3(512), dim3(256), 0, stream>>>(hv, Lp);
  k_pass2<<<dim3(1024), dim3(256), 0, stream>>>(fgT, hv, x, gamma, out);
}

// Round 17
// 158.107 us; speedup vs baseline: 1.0022x; 1.0022x over previous
//
#include <hip/hip_runtime.h>

// SAGAN self-attention, B=4 C=256 H=W=64 (N=4096), CK=32.
//   f = fw@x+fb, g = gw@x+gb, hv = hw@x+hb         (channel 1x1 convs)
//   s[j,m] = sum_k f[k,j] g[k,m];  L[j] = sum_m exp(s[j,m])
//   w[c,j] = hv[c,j]/L[j];  sa[c,m] = sum_j w[c,j] exp(s[j,m]);  out = gamma*sa+x
//
// exp2 pipeline: fgT stores f*log2(e) -> exp2(f'.g) == exp(s), bare v_exp_f32.
// R15 lesson: per-iter __syncthreads (vmcnt0+lgkm0 drain, 4-wave convoy) is the
// binder. This round: (1) hv stored TILE-BLOCKED; pass2 stages via
// global_load_lds (linear LDS dest + inverse-XOR per-lane SOURCE, read side
// unchanged) — no ds_writes, no staging VGPRs; (2) 2 tiles per barrier
// (4-buffer ring) — 32 barriers instead of 64, two independent sub-tile chains
// per barrier scope.
//
// hv tile layout: hvT[b][jt=64][cq=4][row=64][col=64] bf16 (8KB tiles).
//   proj writes it (unpacked); wdiv divides by L + kappa-packs cols in place
//   (within-row). pass2 DMA applies the XOR-swizzle via the source address.
//
// ws layout (bytes) — total 10,747,904:
//   fgT  [4][4096][64]  bf16  @ 0         [n][o]: o<32 = f^T*log2e, o>=32 = g^T
//   hvT  tiles          bf16  @ 2097152   (8,388,608)
//   Lp   [4][4][4096]   f32   @ 10485760  partial L sums (4 m-splits)
//
// XCD map (grid%8==0): b=(bid&7)>>1 pins each batch's fgT+w to one XCD pair L2.

typedef __bf16 bf16x4 __attribute__((ext_vector_type(4)));
typedef __bf16 bf16x8 __attribute__((ext_vector_type(8)));
typedef float  f32x4  __attribute__((ext_vector_type(4)));

static __device__ __forceinline__ bf16x8 cvt8(f32x4 lo, f32x4 hi) {
  bf16x8 r;
  r[0]=(__bf16)lo[0]; r[1]=(__bf16)lo[1]; r[2]=(__bf16)lo[2]; r[3]=(__bf16)lo[3];
  r[4]=(__bf16)hi[0]; r[5]=(__bf16)hi[1]; r[6]=(__bf16)hi[2]; r[7]=(__bf16)hi[3];
  return r;
}
static __device__ __forceinline__ void gload_lds16(const char* g, char* l) {
  __builtin_amdgcn_global_load_lds(
      (const __attribute__((address_space(1))) unsigned int*)g,
      (__attribute__((address_space(3))) unsigned int*)l, 16, 0, 0);
}
// kappa k-map (tied to MFMA D output): e -> k = h*4 + (e&3) + 16*(e>>2).
// Free axes (channel contraction): e -> k = h*8 + e (single 16B load).

// ---------------- proj: x read ONCE; block = 64 n-cols x all 320 m-rows ----------
__global__ __launch_bounds__(512, 1) void k_proj(
    const float* __restrict__ fw, const float* __restrict__ gw,
    const float* __restrict__ hw, const float* __restrict__ x,
    const float* __restrict__ fb, const float* __restrict__ gb,
    const float* __restrict__ hb,
    __bf16* __restrict__ fgT, __bf16* __restrict__ hvT) {
  __shared__ __bf16 Bs[2][64][40];
  const int bid = blockIdx.x;
  const int b = (bid & 7) >> 1;
  const int n0 = (((bid >> 3) << 1) | (bid & 1)) * 64;
  const int t = threadIdx.x, w = t >> 6, lane = t & 63, r16 = lane & 15, h = lane >> 4;
  const int nsub = w & 1, mq = w >> 1;
  const float* xb = x + (size_t)b * (256 * 4096);
  const float* Wp[5];
  #pragma unroll
  for (int mt = 0; mt < 5; ++mt) {
    const int wrow = mq * 80 + mt * 16 + r16;
    Wp[mt] = wrow < 32 ? (fw + wrow * 256)
           : wrow < 64 ? (gw + (wrow - 32) * 256)
                       : (hw + (wrow - 64) * 256);
  }
  const int kk = t >> 4, nc = (t & 15) * 4;
  f32x4 acc[5][2] = {};
  {
    f32x4 xv = *(const f32x4*)&xb[(size_t)kk * 4096 + n0 + nc];
    Bs[0][nc + 0][kk] = (__bf16)xv[0]; Bs[0][nc + 1][kk] = (__bf16)xv[1];
    Bs[0][nc + 2][kk] = (__bf16)xv[2]; Bs[0][nc + 3][kk] = (__bf16)xv[3];
  }
  __syncthreads();
  for (int ks = 0; ks < 8; ++ks) {
    const int cur = ks & 1;
    f32x4 xn;
    if (ks < 7) xn = *(const f32x4*)&xb[(size_t)((ks + 1) * 32 + kk) * 4096 + n0 + nc];
    bf16x8 bf0 = *(const bf16x8*)&Bs[cur][nsub * 32 + r16][h * 8];
    bf16x8 bf1 = *(const bf16x8*)&Bs[cur][nsub * 32 + 16 + r16][h * 8];
    #pragma unroll
    for (int mt = 0; mt < 5; ++mt) {
      f32x4 wlo = *(const f32x4*)(Wp[mt] + ks * 32 + h * 8);
      f32x4 whi = *(const f32x4*)(Wp[mt] + ks * 32 + h * 8 + 4);
      bf16x8 af = cvt8(wlo, whi);
      acc[mt][0] = __builtin_amdgcn_mfma_f32_16x16x32_bf16(af, bf0, acc[mt][0], 0, 0, 0);
      acc[mt][1] = __builtin_amdgcn_mfma_f32_16x16x32_bf16(af, bf1, acc[mt][1], 0, 0, 0);
    }
    if (ks < 7) {
      const int nxt = cur ^ 1;
      Bs[nxt][nc + 0][kk] = (__bf16)xn[0]; Bs[nxt][nc + 1][kk] = (__bf16)xn[1];
      Bs[nxt][nc + 2][kk] = (__bf16)xn[2]; Bs[nxt][nc + 3][kk] = (__bf16)xn[3];
    }
    __syncthreads();
  }
  const size_t tile0 = ((size_t)(b * 64 + (n0 >> 6)) * 4) * 4096;  // [b][jt][cq=0]
  #pragma unroll
  for (int mt = 0; mt < 5; ++mt) {
    #pragma unroll
    for (int nt = 0; nt < 2; ++nt) {
      const int nn = n0 + nsub * 32 + nt * 16 + r16;
      const int nl = nn - n0;                          // 0..63 within tile
      #pragma unroll
      for (int r = 0; r < 4; ++r) {
        const int row = mq * 80 + mt * 16 + h * 4 + r;  // C/D: row=(lane>>4)*4+reg
        const float bias = row < 32 ? fb[row] : (row < 64 ? gb[row - 32] : hb[row - 64]);
        float val = acc[mt][nt][r] + bias;
        if (row < 32) val *= 1.44269504089f;            // f * log2(e)
        if (row < 64) fgT[((size_t)b * 4096 + nn) * 64 + row] = (__bf16)val;
        else {
          const int c = row - 64;
          hvT[tile0 + (size_t)(c >> 6) * 4096 + (c & 63) * 64 + nl] = (__bf16)val;
        }
      }
    }
  }
}

// ---------------- pass1: L[i] = sum_m exp2(f'_i . g_m)  (partial, m-quarter) ----
__global__ __launch_bounds__(256) void k_pass1(const __bf16* __restrict__ fgT,
                                               float* __restrict__ Lp) {
  const int bid = blockIdx.x;
  const int b = (bid & 7) >> 1;
  const int sub = ((bid >> 3) << 1) | (bid & 1);
  const int ms = sub >> 6, ib = sub & 63;
  const int w = threadIdx.x >> 6, lane = threadIdx.x & 63, r16 = lane & 15, h = lane >> 4;
  const int ibase = ib * 64 + w * 16;
  const __bf16* fg = fgT + (size_t)b * (4096 * 64);
  const bf16x8 afrag = *(const bf16x8*)(fg + (size_t)(ibase + r16) * 64 + h * 8);
  const f32x4 zero = {};
  float ls0 = 0.f, ls1 = 0.f, ls2 = 0.f, ls3 = 0.f;
  for (int mt = 0; mt < 64; mt += 2) {
    const int mb = ms * 1024 + mt * 16;
    bf16x8 g0 = *(const bf16x8*)(fg + (size_t)(mb + r16) * 64 + 32 + h * 8);
    bf16x8 g1 = *(const bf16x8*)(fg + (size_t)(mb + 16 + r16) * 64 + 32 + h * 8);
    f32x4 d0 = __builtin_amdgcn_mfma_f32_16x16x32_bf16(afrag, g0, zero, 0, 0, 0);
    f32x4 d1 = __builtin_amdgcn_mfma_f32_16x16x32_bf16(afrag, g1, zero, 0, 0, 0);
    ls0 += __builtin_amdgcn_exp2f(d0[0]) + __builtin_amdgcn_exp2f(d1[0]);
    ls1 += __builtin_amdgcn_exp2f(d0[1]) + __builtin_amdgcn_exp2f(d1[1]);
    ls2 += __builtin_amdgcn_exp2f(d0[2]) + __builtin_amdgcn_exp2f(d1[2]);
    ls3 += __builtin_amdgcn_exp2f(d0[3]) + __builtin_amdgcn_exp2f(d1[3]);
  }
  #pragma unroll
  for (int off = 1; off < 16; off <<= 1) {
    ls0 += __shfl_xor(ls0, off); ls1 += __shfl_xor(ls1, off);
    ls2 += __shfl_xor(ls2, off); ls3 += __shfl_xor(ls3, off);
  }
  if (r16 == 0) {
    f32x4 o = {ls0, ls1, ls2, ls3};
    *(f32x4*)&Lp[(size_t)(b * 4 + ms) * 4096 + ibase + h * 4] = o;
  }
}

// ---------------- wdiv: w = hv/L, kappa-packed cols, in place (tiled) -------
// Thread owns one (row, 32-col group): read all, divide, permute within the
// 64B group (old 16s+4h+b -> new 8h+4s+b), write back. No row-XOR here — the
// XOR swizzle is applied by pass2's DMA source addresses (inverse == forward).
__global__ __launch_bounds__(256) void k_wdiv(__bf16* __restrict__ hvT,
                                              const float* __restrict__ Lp) {
  const int bid = blockIdx.x;                       // 512
  const int b = (bid & 7) >> 1;
  const int chunk = ((bid >> 3) << 1) | (bid & 1);  // 0..127 -> 2 c-rows each
  const int t = threadIdx.x;
  const int r = chunk * 2 + (t >> 7);               // c in 0..255
  const int g = t & 127;                            // 32-col group; j0 = g*32
  const size_t tbase = ((size_t)(b * 64 + (g >> 1)) * 4 + (r >> 6)) * 4096;
  __bf16* p = hvT + tbase + (size_t)(r & 63) * 64 + (g & 1) * 32;
  const float* lp = Lp + (size_t)b * 16384 + g * 32;
  float L[32];
  #pragma unroll
  for (int i = 0; i < 32; i += 4) {
    f32x4 Lv = *(const f32x4*)(lp + i);
    Lv += *(const f32x4*)(lp + i + 4096);
    Lv += *(const f32x4*)(lp + i + 8192);
    Lv += *(const f32x4*)(lp + i + 12288);
    L[i] = Lv[0]; L[i+1] = Lv[1]; L[i+2] = Lv[2]; L[i+3] = Lv[3];
  }
  bf16x4 in[8];
  #pragma unroll
  for (int k = 0; k < 8; ++k) in[k] = *(const bf16x4*)(p + k * 4);
  bf16x4 ov[8];
  #pragma unroll
  for (int h = 0; h < 4; ++h)
    #pragma unroll
    for (int s = 0; s < 2; ++s) {
      bf16x4 v = in[s * 4 + h];                     // old chunk at 16s+4h
      bf16x4 o;
      #pragma unroll
      for (int bb = 0; bb < 4; ++bb)
        o[bb] = (__bf16)((float)v[bb] / L[16 * s + 4 * h + bb]);
      ov[2 * h + s] = o;                            // new chunk at 8h+4s
    }
  #pragma unroll
  for (int k = 0; k < 8; ++k) *(bf16x4*)(p + k * 4) = ov[k];
}

// ---------------- pass2: DMA-staged, 2 tiles/barrier. out = gm*sa + x --------
// 1024 blocks x 256 threads (4 blocks/CU): block = 64c x 64m, waves (msub, jh).
// Per barrier period p: __syncthreads (tiles 2p,2p+1 resident via DMA issued
// last period); issue DMA for tiles 2p+2,2p+3 (other buffer pair, drained by
// NEXT barrier -> full period of latency cover); compute both sub-tiles
// (independent chains, compiler interleaves). DMA: linear LDS dest, per-lane
// source pre-applies the XOR involution; reads identical to R14 (0 conflicts).
__global__ __launch_bounds__(256, 4) void k_pass2(const __bf16* __restrict__ fgT,
    const __bf16* __restrict__ hvT, const float* __restrict__ x,
    const float* __restrict__ gamma, float* __restrict__ out) {
  __shared__ char wS[4][8192];                      // 32 KB ring
  const int bid = blockIdx.x;
  const int b = (bid & 7) >> 1;                     // XCD pair per batch
  const int cq = (bid >> 3) & 3;                    // c-quarter: rows cq*64..+63
  const int mblk = ((bid >> 5) << 1) | (bid & 1);   // 0..63
  const int t = threadIdx.x, w = t >> 6, lane = t & 63, r16 = lane & 15, h = lane >> 4;
  const int jh = w & 1, msub = w >> 1;
  const int mbase = mblk * 64 + msub * 32;
  const __bf16* fg = fgT + (size_t)b * (4096 * 64);
  // gfrags: MFMA1 B operands (contiguous channel map), invariant over j
  const bf16x8 gf0 = *(const bf16x8*)(fg + (size_t)(mbase + r16) * 64 + 32 + h * 8);
  const bf16x8 gf1 = *(const bf16x8*)(fg + (size_t)(mbase + 16 + r16) * 64 + 32 + h * 8);
  // DMA lane geometry: LDS dest d = w*2048 + l*16 (linear); source applies XOR
  const int d0 = w * 2048 + lane * 16;
  const int p0 = (d0 & ~127) | ((d0 & 127) ^ (((d0 >> 7) & 7) << 4));
  const char* srcLane = (const char*)hvT + (size_t)b * 2097152
                      + (size_t)cq * 8192 + p0;     // + T*32768 (+1024 for k=1)
  char* const ldsW = &wS[0][0] + w * 2048;          // + buf*8192 (+1024 for k=1)
  // read side (unchanged from R14, conflicts=0): one b128 per c-tile
  const int rsw = (r16 & 7) << 4;
  const int roff = ((jh * 64 + h * 16) ^ rsw);
  const int jwave = jh * 32, h8 = h * 8;
  const f32x4 zero = {};

  f32x4 acc[4] = {};
  f32x4 acc2[4] = {};

  // prologue: DMA tiles 0,1 into bufs 0,1
  gload_lds16(srcLane,          ldsW);
  gload_lds16(srcLane + 1024,   ldsW + 1024);
  gload_lds16(srcLane + 32768,        ldsW + 8192);
  gload_lds16(srcLane + 32768 + 1024, ldsW + 8192 + 1024);

  for (int p = 0; p < 32; ++p) {
    __syncthreads();                                // tiles 2p,2p+1 resident
    if (p < 31) {                                   // DMA tiles 2p+2, 2p+3
      const char* s2 = srcLane + (size_t)(2 * p + 2) * 32768;
      char* l2 = ldsW + ((p + 1) & 1) * 16384;
      gload_lds16(s2,                 l2);
      gload_lds16(s2 + 1024,          l2 + 1024);
      gload_lds16(s2 + 32768,         l2 + 8192);
      gload_lds16(s2 + 32768 + 1024,  l2 + 8192 + 1024);
    }
    const char* bufp = &wS[(p & 1) * 2][0];
    #pragma unroll
    for (int sub = 0; sub < 2; ++sub) {
      const int T = 2 * p + sub;
      const char* buf = bufp + sub * 8192;
      // f frags for tile T (own jh half)
      bf16x8 fq0 = *(const bf16x8*)(fg + (size_t)(T * 64 + jwave + r16) * 64 + h8);
      bf16x8 fq1 = *(const bf16x8*)(fg + (size_t)(T * 64 + jwave + 16 + r16) * 64 + h8);
      // a frags: one b128 per c-tile
      bf16x8 a0 = *(const bf16x8*)(buf + ( 0 + r16) * 128 + roff);
      bf16x8 a1 = *(const bf16x8*)(buf + (16 + r16) * 128 + roff);
      bf16x8 a2 = *(const bf16x8*)(buf + (32 + r16) * 128 + roff);
      bf16x8 a3 = *(const bf16x8*)(buf + (48 + r16) * 128 + roff);
      // MFMA1 x4 + exp2 -> ef0/ef1
      f32x4 d0v = __builtin_amdgcn_mfma_f32_16x16x32_bf16(fq0, gf0, zero, 0, 0, 0);
      f32x4 d1v = __builtin_amdgcn_mfma_f32_16x16x32_bf16(fq1, gf0, zero, 0, 0, 0);
      f32x4 d2v = __builtin_amdgcn_mfma_f32_16x16x32_bf16(fq0, gf1, zero, 0, 0, 0);
      f32x4 d3v = __builtin_amdgcn_mfma_f32_16x16x32_bf16(fq1, gf1, zero, 0, 0, 0);
      bf16x8 ef0, ef1;
      #pragma unroll
      for (int r = 0; r < 4; ++r) {
        ef0[r]     = (__bf16)__builtin_amdgcn_exp2f(d0v[r]);
        ef0[4 + r] = (__bf16)__builtin_amdgcn_exp2f(d1v[r]);
        ef1[r]     = (__bf16)__builtin_amdgcn_exp2f(d2v[r]);
        ef1[4 + r] = (__bf16)__builtin_amdgcn_exp2f(d3v[r]);
      }
      // MFMA2 x8
      acc[0]  = __builtin_amdgcn_mfma_f32_16x16x32_bf16(a0, ef0, acc[0],  0, 0, 0);
      acc2[0] = __builtin_amdgcn_mfma_f32_16x16x32_bf16(a0, ef1, acc2[0], 0, 0, 0);
      acc[1]  = __builtin_amdgcn_mfma_f32_16x16x32_bf16(a1, ef0, acc[1],  0, 0, 0);
      acc2[1] = __builtin_amdgcn_mfma_f32_16x16x32_bf16(a1, ef1, acc2[1], 0, 0, 0);
      acc[2]  = __builtin_amdgcn_mfma_f32_16x16x32_bf16(a2, ef0, acc[2],  0, 0, 0);
      acc2[2] = __builtin_amdgcn_mfma_f32_16x16x32_bf16(a2, ef1, acc2[2], 0, 0, 0);
      acc[3]  = __builtin_amdgcn_mfma_f32_16x16x32_bf16(a3, ef0, acc[3],  0, 0, 0);
      acc2[3] = __builtin_amdgcn_mfma_f32_16x16x32_bf16(a3, ef1, acc2[3], 0, 0, 0);
    }
  }

  // epilogue: jh=1 waves dump partials into wS (dead), jh=0 adds + writes out.
  __syncthreads();
  float* red = (float*)wS;
  const int region = msub * 2048;                   // 2 regions x 8KB (floats)
  if (jh == 1) {
    #pragma unroll
    for (int ct = 0; ct < 4; ++ct) {
      *(f32x4*)&red[region + ((ct * 2 + 0) * 64 + lane) * 4] = acc[ct];
      *(f32x4*)&red[region + ((ct * 2 + 1) * 64 + lane) * 4] = acc2[ct];
    }
  }
  __syncthreads();
  if (jh == 0) {
    const float gm = gamma[0];
    const float* xb = x + (size_t)b * (256 * 4096);
    float* ob = out + (size_t)b * (256 * 4096);
    #pragma unroll
    for (int ct = 0; ct < 4; ++ct) {
      #pragma unroll
      for (int mt = 0; mt < 2; ++mt) {
        f32x4 o = *(const f32x4*)&red[region + ((ct * 2 + mt) * 64 + lane) * 4];
        o += (mt == 0) ? acc[ct] : acc2[ct];
        #pragma unroll
        for (int r = 0; r < 4; ++r) {
          const int c = cq * 64 + ct * 16 + h * 4 + r;
          const size_t idx = (size_t)c * 4096 + (mbase + mt * 16 + r16);
          ob[idx] = gm * o[r] + xb[idx];
        }
      }
    }
  }
}

extern "C" void kernel_launch(void* const* d_in, const int* in_sizes, int n_in,
                              void* d_out, int out_size, void* d_ws, size_t ws_size,
                              hipStream_t stream) {
  const float* x     = (const float*)d_in[0];
  const float* fw    = (const float*)d_in[1];
  const float* fb    = (const float*)d_in[2];
  const float* gw    = (const float*)d_in[3];
  const float* gb    = (const float*)d_in[4];
  const float* hw    = (const float*)d_in[5];
  const float* hb    = (const float*)d_in[6];
  const float* gamma = (const float*)d_in[7];
  float* out = (float*)d_out;

  char* wsb = (char*)d_ws;
  __bf16* fgT = (__bf16*)(wsb);
  __bf16* hvT = (__bf16*)(wsb + 2097152);
  float*  Lp  = (float*) (wsb + 10485760);

  k_proj<<<dim3(256), dim3(512), 0, stream>>>(fw, gw, hw, x, fb, gb, hb, fgT, hvT);
  k_pass1<<<dim3(1024), dim3(256), 0, stream>>>(fgT, Lp);
  k_wdiv<<<dim3(512), dim3(256), 0, stream>>>(hvT, Lp);
  k_pass2<<<dim3(1024), dim3(256), 0, stream>>>(fgT, hvT, x, gamma, out);
}